// Round 1
// baseline (635.683 us; speedup 1.0000x reference)
//
#include <hip/hip_runtime.h>
#include <math.h>
#include <limits.h>

#define TPB 256

union F4 { float4 v; float f[4]; };

__device__ __forceinline__ double Ffunc(double x, double y) {
    const double LOG3 = 1.0986122886681098;
    double e1 = exp(-x * x - (y + 1.0) * (y + 1.0));
    double e2 = exp(-x * x - y * y);
    double e3 = exp(-(x + 1.0) * (x + 1.0) - y * y);
    double x3 = x * x * x;
    double y5 = y * y * y * y * y;
    // 3(1-x)^2 e1 - 10(x/5 - x^3 - y^5) e2 - 1/(3^e3)
    return 3.0 * (1.0 - x) * (1.0 - x) * e1
         - 10.0 * (x * 0.2 - x3 - y5) * e2
         - exp(-LOG3 * e3);
}

__global__ __launch_bounds__(TPB, 1)
void fused_mlp(const int* __restrict__ data, const float* __restrict__ embed,
               const float* __restrict__ W1, const float* __restrict__ b1,
               const float* __restrict__ W2, const float* __restrict__ b2,
               const float* __restrict__ W3, const float* __restrict__ b3,
               double* __restrict__ wsF, float2* __restrict__ wsO,
               int* __restrict__ wsI, int N)
{
    // LDS: W1s[128][132] (reused as h2s[64][68] later) + W2s[128][68] + xs[64][132]
    __shared__ __align__(16) float regionA[128 * 132];
    __shared__ __align__(16) float W2s[128 * 68];
    __shared__ __align__(16) float xs[64 * 132];
    __shared__ float embs[48];
    __shared__ float b1s[128];
    __shared__ float b2s[64];
    __shared__ float W3s[128];
    __shared__ float b3s[2];

    const int tid = threadIdx.x;
    const int base = blockIdx.x << 6;               // *64
    const int validRows = min(64, N - base);

    if (tid < 48) embs[tid] = embed[tid];
    if (tid < 128) { b1s[tid] = b1[tid]; W3s[tid] = W3[tid]; }
    else if (tid < 192) b2s[tid - 128] = b2[tid - 128];
    if (tid < 2) b3s[tid] = b3[tid];
    __syncthreads();  // embs ready before gather below

    // Stage W1 -> regionA [128][132]
    for (int u = tid; u < 4096; u += TPB) {
        float4 v = ((const float4*)W1)[u];
        int lin = u << 2, k = lin >> 7, j = lin & 127;
        *(float4*)&regionA[k * 132 + j] = v;
    }
    // Stage W2 -> W2s [128][68]
    for (int u = tid; u < 2048; u += TPB) {
        float4 v = ((const float4*)W2)[u];
        int lin = u << 2, k = lin >> 6, j = lin & 63;
        *(float4*)&W2s[k * 68 + j] = v;
    }
    // Stage data-tile -> xs via embed gather
    const int nInts = validRows << 7;
    for (int u = tid; u < 2048; u += TPB) {
        int lin = u << 2;
        float4 xv = make_float4(0.f, 0.f, 0.f, 0.f);
        if (lin < nInts) {
            int4 d = ((const int4*)data)[(size_t)base * 32 + (size_t)u];
            xv = make_float4(embs[d.x], embs[d.y], embs[d.z], embs[d.w]);
        }
        int i = lin >> 7, k = lin & 127;
        *(float4*)&xs[i * 132 + k] = xv;
    }
    __syncthreads();

    const int ti = tid >> 4, tj = tid & 15;
    const int i0 = ti << 2;
    const int c0 = tj << 2;          // cols c0..c0+3
    const int c1 = 64 + (tj << 2);   // cols c1..c1+3

    // ---------------- Layer 1: h1 = relu(x @ W1 + b1), 64x128 ----------------
    float acc[4][8];
    #pragma unroll
    for (int r = 0; r < 4; ++r)
        #pragma unroll
        for (int c = 0; c < 4; ++c) { acc[r][c] = b1s[c0 + c]; acc[r][c + 4] = b1s[c1 + c]; }

    #pragma unroll 2
    for (int k4 = 0; k4 < 128; k4 += 4) {
        F4 xv[4];
        #pragma unroll
        for (int r = 0; r < 4; ++r) xv[r].v = *(const float4*)&xs[(i0 + r) * 132 + k4];
        #pragma unroll
        for (int kk = 0; kk < 4; ++kk) {
            F4 wA, wB;
            wA.v = *(const float4*)&regionA[(k4 + kk) * 132 + c0];
            wB.v = *(const float4*)&regionA[(k4 + kk) * 132 + c1];
            #pragma unroll
            for (int r = 0; r < 4; ++r) {
                float xval = xv[r].f[kk];
                #pragma unroll
                for (int c = 0; c < 4; ++c) {
                    acc[r][c]     = fmaf(xval, wA.f[c], acc[r][c]);
                    acc[r][c + 4] = fmaf(xval, wB.f[c], acc[r][c + 4]);
                }
            }
        }
    }
    __syncthreads();     // all reads of xs done before overwrite
    #pragma unroll
    for (int r = 0; r < 4; ++r) {
        F4 a, b;
        #pragma unroll
        for (int c = 0; c < 4; ++c) {
            a.f[c] = fmaxf(acc[r][c], 0.f);
            b.f[c] = fmaxf(acc[r][c + 4], 0.f);
        }
        *(float4*)&xs[(i0 + r) * 132 + c0] = a.v;
        *(float4*)&xs[(i0 + r) * 132 + c1] = b.v;
    }
    __syncthreads();

    // ---------------- Layer 2: h2 = tanh(h1 @ W2 + b2), 64x64 ----------------
    float acc2[4][4];
    #pragma unroll
    for (int r = 0; r < 4; ++r)
        #pragma unroll
        for (int c = 0; c < 4; ++c) acc2[r][c] = b2s[c0 + c];

    #pragma unroll 2
    for (int k4 = 0; k4 < 128; k4 += 4) {
        F4 hv[4];
        #pragma unroll
        for (int r = 0; r < 4; ++r) hv[r].v = *(const float4*)&xs[(i0 + r) * 132 + k4];
        #pragma unroll
        for (int kk = 0; kk < 4; ++kk) {
            F4 w;
            w.v = *(const float4*)&W2s[(k4 + kk) * 68 + c0];
            #pragma unroll
            for (int r = 0; r < 4; ++r)
                #pragma unroll
                for (int c = 0; c < 4; ++c)
                    acc2[r][c] = fmaf(hv[r].f[kk], w.f[c], acc2[r][c]);
        }
    }
    // regionA (W1) reads finished before the pre-relu barrier; safe to reuse as h2s.
    float* h2s = regionA;  // [64][68]
    #pragma unroll
    for (int r = 0; r < 4; ++r) {
        F4 t;
        #pragma unroll
        for (int c = 0; c < 4; ++c) t.f[c] = tanhf(acc2[r][c]);
        *(float4*)&h2s[(i0 + r) * 68 + c0] = t.v;
    }
    __syncthreads();

    // ---------------- Layer 3 + F + per-block argmax (wave 0 only) ----------------
    if (tid < 64) {
        int r = tid;
        double Fv = -INFINITY;
        int idx = INT_MAX;
        float o0 = 0.f, o1 = 0.f;
        if (r < validRows) {
            float a0 = b3s[0], a1 = b3s[1];
            #pragma unroll 8
            for (int k = 0; k < 64; ++k) {
                float h = h2s[r * 68 + k];
                a0 = fmaf(h, W3s[2 * k], a0);
                a1 = fmaf(h, W3s[2 * k + 1], a1);
            }
            o0 = a0; o1 = a1;
            Fv = Ffunc((double)o0, (double)o1);
            idx = base + r;
        }
        // 64-lane argmax reduce, first-index tie-break
        #pragma unroll
        for (int m = 32; m > 0; m >>= 1) {
            double Fo = __shfl_xor(Fv, m, 64);
            int io    = __shfl_xor(idx, m, 64);
            float a0  = __shfl_xor(o0, m, 64);
            float a1  = __shfl_xor(o1, m, 64);
            if (Fo > Fv || (Fo == Fv && io < idx)) { Fv = Fo; idx = io; o0 = a0; o1 = a1; }
        }
        if (tid == 0) {
            wsF[blockIdx.x] = Fv;
            wsI[blockIdx.x] = idx;
            wsO[blockIdx.x] = make_float2(o0, o1);
        }
    }
}

__global__ __launch_bounds__(TPB, 1)
void reduce_cands(const double* __restrict__ wsF, const float2* __restrict__ wsO,
                  const int* __restrict__ wsI, int nB, float* __restrict__ out)
{
    __shared__ double sF[TPB];
    __shared__ int sI[TPB];
    __shared__ float2 sO[TPB];
    const int tid = threadIdx.x;
    double Fv = -INFINITY; int idx = INT_MAX; float2 o = make_float2(0.f, 0.f);
    for (int u = tid; u < nB; u += TPB) {
        double f = wsF[u]; int i = wsI[u];
        if (f > Fv || (f == Fv && i < idx)) { Fv = f; idx = i; o = wsO[u]; }
    }
    sF[tid] = Fv; sI[tid] = idx; sO[tid] = o;
    __syncthreads();
    if (tid == 0) {
        for (int u = 1; u < TPB; ++u) {
            if (sF[u] > Fv || (sF[u] == Fv && sI[u] < idx)) { Fv = sF[u]; idx = sI[u]; o = sO[u]; }
        }
        out[0] = o.x;
        out[1] = o.y;
    }
}

extern "C" void kernel_launch(void* const* d_in, const int* in_sizes, int n_in,
                              void* d_out, int out_size, void* d_ws, size_t ws_size,
                              hipStream_t stream) {
    const int*   data  = (const int*)d_in[0];
    const float* embed = (const float*)d_in[1];
    const float* W1    = (const float*)d_in[2];
    const float* b1    = (const float*)d_in[3];
    const float* W2    = (const float*)d_in[4];
    const float* b2    = (const float*)d_in[5];
    const float* W3    = (const float*)d_in[6];
    const float* b3    = (const float*)d_in[7];

    const int N = in_sizes[0] / 128;
    const int nTiles = (N + 63) >> 6;

    char* ws = (char*)d_ws;
    double* wsF = (double*)ws;
    float2* wsO = (float2*)(ws + (size_t)nTiles * 8);
    int*    wsI = (int*)(ws + (size_t)nTiles * 16);

    fused_mlp<<<nTiles, TPB, 0, stream>>>(data, embed, W1, b1, W2, b2, W3, b3,
                                          wsF, wsO, wsI, N);
    reduce_cands<<<1, TPB, 0, stream>>>(wsF, wsO, wsI, nTiles, (float*)d_out);
}

// Round 2
// 412.421 us; speedup vs baseline: 1.5413x; 1.5413x over previous
//
#include <hip/hip_runtime.h>
#include <math.h>
#include <limits.h>

#define TPB 256

union F4 { float4 v; float f[4]; };

__device__ __forceinline__ double Ffunc(double x, double y) {
    const double LOG3 = 1.0986122886681098;
    double e1 = exp(-x * x - (y + 1.0) * (y + 1.0));
    double e2 = exp(-x * x - y * y);
    double e3 = exp(-(x + 1.0) * (x + 1.0) - y * y);
    double x3 = x * x * x;
    double y5 = y * y * y * y * y;
    // 3(1-x)^2 e1 - 10(x/5 - x^3 - y^5) e2 - 1/(3^e3)
    return 3.0 * (1.0 - x) * (1.0 - x) * e1
         - 10.0 * (x * 0.2 - x3 - y5) * e2
         - exp(-LOG3 * e3);
}

__global__ __launch_bounds__(TPB, 4)
void fused_mlp(const int* __restrict__ data, const float* __restrict__ embed,
               const float* __restrict__ W1, const float* __restrict__ b1,
               const float* __restrict__ W2, const float* __restrict__ b2,
               const float* __restrict__ W3, const float* __restrict__ b3,
               double* __restrict__ wsF, float2* __restrict__ wsO,
               int* __restrict__ wsI, int N)
{
    // Only the activation tile lives in LDS (x -> h1 -> h2 in place).
    // W1/W2 are 96 KB total chip-wide: read straight from global (L1/L2-hit,
    // 16-lane-broadcast addresses). LDS ~35 KB -> 4 blocks/CU.
    __shared__ __align__(16) float xs[64 * 132];
    __shared__ float embs[48];
    __shared__ float b1s[128];
    __shared__ float b2s[64];
    __shared__ float W3s[128];
    __shared__ float b3s[2];

    const int tid = threadIdx.x;
    const int base = blockIdx.x << 6;               // *64
    const int validRows = min(64, N - base);

    if (tid < 48) embs[tid] = embed[tid];
    if (tid < 128) { b1s[tid] = b1[tid]; W3s[tid] = W3[tid]; }
    else if (tid < 192) b2s[tid - 128] = b2[tid - 128];
    if (tid < 2) b3s[tid] = b3[tid];
    __syncthreads();  // embs ready before gather below

    // Stage data-tile -> xs via embed gather
    const int nInts = validRows << 7;
    for (int u = tid; u < 2048; u += TPB) {
        int lin = u << 2;
        float4 xv = make_float4(0.f, 0.f, 0.f, 0.f);
        if (lin < nInts) {
            int4 d = ((const int4*)data)[(size_t)base * 32 + (size_t)u];
            xv = make_float4(embs[d.x], embs[d.y], embs[d.z], embs[d.w]);
        }
        int i = lin >> 7, k = lin & 127;
        *(float4*)&xs[i * 132 + k] = xv;
    }
    __syncthreads();

    const int ti = tid >> 4, tj = tid & 15;
    const int i0 = ti << 2;
    const int c0 = tj << 2;          // cols c0..c0+3
    const int c1 = 64 + (tj << 2);   // cols c1..c1+3

    const float4* w1v = (const float4*)W1;   // [128 rows][32 float4]
    const float4* w2v = (const float4*)W2;   // [128 rows][16 float4]

    // ---------------- Layer 1: h1 = relu(x @ W1 + b1), 64x128 ----------------
    float acc[4][8];
    #pragma unroll
    for (int r = 0; r < 4; ++r)
        #pragma unroll
        for (int c = 0; c < 4; ++c) { acc[r][c] = b1s[c0 + c]; acc[r][c + 4] = b1s[c1 + c]; }

    #pragma unroll 2
    for (int k4 = 0; k4 < 128; k4 += 4) {
        F4 xv[4];
        #pragma unroll
        for (int r = 0; r < 4; ++r) xv[r].v = *(const float4*)&xs[(i0 + r) * 132 + k4];
        #pragma unroll
        for (int kk = 0; kk < 4; ++kk) {
            F4 wA, wB;
            wA.v = w1v[((k4 + kk) << 5) + tj];
            wB.v = w1v[((k4 + kk) << 5) + 16 + tj];
            #pragma unroll
            for (int r = 0; r < 4; ++r) {
                float xval = xv[r].f[kk];
                #pragma unroll
                for (int c = 0; c < 4; ++c) {
                    acc[r][c]     = fmaf(xval, wA.f[c], acc[r][c]);
                    acc[r][c + 4] = fmaf(xval, wB.f[c], acc[r][c + 4]);
                }
            }
        }
    }
    __syncthreads();     // all reads of xs done before overwrite
    #pragma unroll
    for (int r = 0; r < 4; ++r) {
        F4 a, b;
        #pragma unroll
        for (int c = 0; c < 4; ++c) {
            a.f[c] = fmaxf(acc[r][c], 0.f);
            b.f[c] = fmaxf(acc[r][c + 4], 0.f);
        }
        *(float4*)&xs[(i0 + r) * 132 + c0] = a.v;
        *(float4*)&xs[(i0 + r) * 132 + c1] = b.v;
    }
    __syncthreads();

    // ---------------- Layer 2: h2 = tanh(h1 @ W2 + b2), 64x64 ----------------
    float acc2[4][4];
    #pragma unroll
    for (int r = 0; r < 4; ++r)
        #pragma unroll
        for (int c = 0; c < 4; ++c) acc2[r][c] = b2s[c0 + c];

    #pragma unroll 2
    for (int k4 = 0; k4 < 128; k4 += 4) {
        F4 hv[4];
        #pragma unroll
        for (int r = 0; r < 4; ++r) hv[r].v = *(const float4*)&xs[(i0 + r) * 132 + k4];
        #pragma unroll
        for (int kk = 0; kk < 4; ++kk) {
            F4 w;
            w.v = w2v[((k4 + kk) << 4) + tj];
            #pragma unroll
            for (int r = 0; r < 4; ++r)
                #pragma unroll
                for (int c = 0; c < 4; ++c)
                    acc2[r][c] = fmaf(hv[r].f[kk], w.f[c], acc2[r][c]);
        }
    }
    __syncthreads();     // all reads of h1 (xs) done before overwrite
    #pragma unroll
    for (int r = 0; r < 4; ++r) {
        F4 t;
        #pragma unroll
        for (int c = 0; c < 4; ++c) t.f[c] = tanhf(acc2[r][c]);
        *(float4*)&xs[(i0 + r) * 132 + c0] = t.v;   // h2 tile, cols 0..63
    }
    __syncthreads();

    // ---------------- Layer 3 + F + per-block argmax (wave 0 only) ----------------
    if (tid < 64) {
        int r = tid;
        double Fv = -INFINITY;
        int idx = INT_MAX;
        float o0 = 0.f, o1 = 0.f;
        if (r < validRows) {
            float a0 = b3s[0], a1 = b3s[1];
            #pragma unroll 8
            for (int k = 0; k < 64; ++k) {
                float h = xs[r * 132 + k];
                a0 = fmaf(h, W3s[2 * k], a0);
                a1 = fmaf(h, W3s[2 * k + 1], a1);
            }
            o0 = a0; o1 = a1;
            Fv = Ffunc((double)o0, (double)o1);
            idx = base + r;
        }
        // 64-lane argmax reduce, first-index tie-break
        #pragma unroll
        for (int m = 32; m > 0; m >>= 1) {
            double Fo = __shfl_xor(Fv, m, 64);
            int io    = __shfl_xor(idx, m, 64);
            float a0  = __shfl_xor(o0, m, 64);
            float a1  = __shfl_xor(o1, m, 64);
            if (Fo > Fv || (Fo == Fv && io < idx)) { Fv = Fo; idx = io; o0 = a0; o1 = a1; }
        }
        if (tid == 0) {
            wsF[blockIdx.x] = Fv;
            wsI[blockIdx.x] = idx;
            wsO[blockIdx.x] = make_float2(o0, o1);
        }
    }
}

__global__ __launch_bounds__(TPB, 1)
void reduce_cands(const double* __restrict__ wsF, const float2* __restrict__ wsO,
                  const int* __restrict__ wsI, int nB, float* __restrict__ out)
{
    __shared__ double sF[TPB];
    __shared__ int sI[TPB];
    __shared__ float2 sO[TPB];
    const int tid = threadIdx.x;
    double Fv = -INFINITY; int idx = INT_MAX; float2 o = make_float2(0.f, 0.f);
    for (int u = tid; u < nB; u += TPB) {
        double f = wsF[u]; int i = wsI[u];
        if (f > Fv || (f == Fv && i < idx)) { Fv = f; idx = i; o = wsO[u]; }
    }
    sF[tid] = Fv; sI[tid] = idx; sO[tid] = o;
    __syncthreads();
    if (tid == 0) {
        for (int u = 1; u < TPB; ++u) {
            if (sF[u] > Fv || (sF[u] == Fv && sI[u] < idx)) { Fv = sF[u]; idx = sI[u]; o = sO[u]; }
        }
        out[0] = o.x;
        out[1] = o.y;
    }
}

extern "C" void kernel_launch(void* const* d_in, const int* in_sizes, int n_in,
                              void* d_out, int out_size, void* d_ws, size_t ws_size,
                              hipStream_t stream) {
    const int*   data  = (const int*)d_in[0];
    const float* embed = (const float*)d_in[1];
    const float* W1    = (const float*)d_in[2];
    const float* b1    = (const float*)d_in[3];
    const float* W2    = (const float*)d_in[4];
    const float* b2    = (const float*)d_in[5];
    const float* W3    = (const float*)d_in[6];
    const float* b3    = (const float*)d_in[7];

    const int N = in_sizes[0] / 128;
    const int nTiles = (N + 63) >> 6;

    char* ws = (char*)d_ws;
    double* wsF = (double*)ws;
    float2* wsO = (float2*)(ws + (size_t)nTiles * 8);
    int*    wsI = (int*)(ws + (size_t)nTiles * 16);

    fused_mlp<<<nTiles, TPB, 0, stream>>>(data, embed, W1, b1, W2, b2, W3, b3,
                                          wsF, wsO, wsI, N);
    reduce_cands<<<1, TPB, 0, stream>>>(wsF, wsO, wsI, nTiles, (float*)d_out);
}

// Round 3
// 184.797 us; speedup vs baseline: 3.4399x; 2.2317x over previous
//
#include <hip/hip_runtime.h>
#include <math.h>
#include <limits.h>

typedef __attribute__((ext_vector_type(8))) short short8v;
typedef __attribute__((ext_vector_type(4))) float f32x4;

union U4 { uint4 u; short8v s; };
union F4 { float4 v; float f[4]; };

__device__ __forceinline__ uint32_t bf_hi_bits(float x) {
    uint32_t u = __float_as_uint(x);
    return (u + 0x7FFFu + ((u >> 16) & 1u)) >> 16;
}

__device__ __forceinline__ double Ffunc(double x, double y) {
    const double LOG3 = 1.0986122886681098;
    double e1 = exp(-x * x - (y + 1.0) * (y + 1.0));
    double e2 = exp(-x * x - y * y);
    double e3 = exp(-(x + 1.0) * (x + 1.0) - y * y);
    double x3 = x * x * x;
    double y5 = y * y * y * y * y;
    return 3.0 * (1.0 - x) * (1.0 - x) * e1
         - 10.0 * (x * 0.2 - x3 - y5) * e2
         - exp(-LOG3 * e3);
}

// Pack W1 (128x128) and W2 (128x64) into MFMA B-fragment order, bf16 hi/lo planes.
// B-frag elem j of lane l in tile (t,s): W[k][n], k = 32s + 8*(l>>4) + j, n = 16t + (l&15).
// Stored as uint4 per lane (elem 2d in low half of dword d).
__global__ void pack_weights(const float* __restrict__ W1, const float* __restrict__ W2,
                             uint4* __restrict__ w1h, uint4* __restrict__ w1l,
                             uint4* __restrict__ w2h, uint4* __restrict__ w2l)
{
    const int b = blockIdx.x;
    const int tid = threadIdx.x;
    const int s = tid >> 6, lane = tid & 63, g = lane >> 4, c = lane & 15;
    const float* W; uint4 *oh, *ol; int t, ldw;
    if (b < 8) { W = W1; oh = w1h; ol = w1l; t = b;     ldw = 128; }
    else       { W = W2; oh = w2h; ol = w2l; t = b - 8; ldw = 64;  }
    const int n = 16 * t + c;
    uint32_t hb[8], lb[8];
    #pragma unroll
    for (int j = 0; j < 8; ++j) {
        int k = 32 * s + 8 * g + j;
        float v = W[k * ldw + n];
        uint32_t h = bf_hi_bits(v);
        float fh = __uint_as_float(h << 16);
        uint32_t l = bf_hi_bits(v - fh);
        hb[j] = h; lb[j] = l;
    }
    uint4 H = make_uint4(hb[0] | (hb[1] << 16), hb[2] | (hb[3] << 16),
                         hb[4] | (hb[5] << 16), hb[6] | (hb[7] << 16));
    uint4 L = make_uint4(lb[0] | (lb[1] << 16), lb[2] | (lb[3] << 16),
                         lb[4] | (lb[5] << 16), lb[6] | (lb[7] << 16));
    oh[(t * 4 + s) * 64 + lane] = H;
    ol[(t * 4 + s) * 64 + lane] = L;
}

__global__ __launch_bounds__(256, 4)
void fused_mlp(const int* __restrict__ data, const float* __restrict__ embed,
               const float* __restrict__ b1, const float* __restrict__ b2,
               const float* __restrict__ W3, const float* __restrict__ b3,
               const uint4* __restrict__ w1h, const uint4* __restrict__ w1l,
               const uint4* __restrict__ w2h, const uint4* __restrict__ w2l,
               double* __restrict__ wsF, float2* __restrict__ wsO,
               int* __restrict__ wsI, int N)
{
    __shared__ __align__(16) float h1s[4][16 * 132];   // per-wave h1 strip (reused for h2)
    __shared__ uint32_t embs_pk[48];                   // (bf16_hi << 16) | bf16_lo
    __shared__ float b1s[128], W3s[128], b2s[64], b3s[2];
    __shared__ double candF[4];
    __shared__ int candI[4];
    __shared__ float2 candO[4];

    const int tid = threadIdx.x;
    if (tid < 48) {
        float e = embed[tid];
        uint32_t h = bf_hi_bits(e);
        float fh = __uint_as_float(h << 16);
        uint32_t l = bf_hi_bits(e - fh);
        embs_pk[tid] = (h << 16) | l;
    }
    if (tid < 128) { b1s[tid] = b1[tid]; W3s[tid] = W3[tid]; }
    else if (tid < 192) b2s[tid - 128] = b2[tid - 128];
    if (tid < 2) b3s[tid] = b3[tid];
    __syncthreads();

    const int w = tid >> 6, lane = tid & 63, g = lane >> 4, c = lane & 15;
    const int base = blockIdx.x << 6;

    // ---- x A-fragments (hi/lo) straight from data-gather, in registers ----
    const int rowA = base + 16 * w + c;
    const size_t drow = (size_t)min(rowA, N - 1) * 128;
    uint4 xh[4], xl[4];
    #pragma unroll
    for (int s = 0; s < 4; ++s) {
        const int4* dp = (const int4*)&data[drow + 32 * s + 8 * g];
        int4 d0 = dp[0], d1 = dp[1];
        int id0 = d0.x, id1 = d0.y, id2 = d0.z, id3 = d0.w;
        int id4 = d1.x, id5 = d1.y, id6 = d1.z, id7 = d1.w;
        uint32_t p0 = embs_pk[id0], p1 = embs_pk[id1], p2 = embs_pk[id2], p3 = embs_pk[id3];
        uint32_t p4 = embs_pk[id4], p5 = embs_pk[id5], p6 = embs_pk[id6], p7 = embs_pk[id7];
        xh[s] = make_uint4((p1 & 0xFFFF0000u) | (p0 >> 16), (p3 & 0xFFFF0000u) | (p2 >> 16),
                           (p5 & 0xFFFF0000u) | (p4 >> 16), (p7 & 0xFFFF0000u) | (p6 >> 16));
        xl[s] = make_uint4((p1 << 16) | (p0 & 0xFFFFu), (p3 << 16) | (p2 & 0xFFFFu),
                           (p5 << 16) | (p4 & 0xFFFFu), (p7 << 16) | (p6 & 0xFFFFu));
    }

    // ---- Layer 1: h1 = relu(x @ W1 + b1) via 3-term split MFMA ----
    f32x4 acc[8];
    #pragma unroll
    for (int t = 0; t < 8; ++t) { float bv = b1s[16 * t + c]; acc[t] = (f32x4){bv, bv, bv, bv}; }
    #pragma unroll
    for (int t = 0; t < 8; ++t) {
        #pragma unroll
        for (int s = 0; s < 4; ++s) {
            U4 bh, bl, ah, al;
            bh.u = w1h[(t * 4 + s) * 64 + lane];
            bl.u = w1l[(t * 4 + s) * 64 + lane];
            ah.u = xh[s]; al.u = xl[s];
            acc[t] = __builtin_amdgcn_mfma_f32_16x16x32_bf16(ah.s, bh.s, acc[t], 0, 0, 0);
            acc[t] = __builtin_amdgcn_mfma_f32_16x16x32_bf16(al.s, bh.s, acc[t], 0, 0, 0);
            acc[t] = __builtin_amdgcn_mfma_f32_16x16x32_bf16(ah.s, bl.s, acc[t], 0, 0, 0);
        }
    }
    float* myh = h1s[w];
    // D layout: row = 4g + r, col = 16t + c  (m89-verified)
    #pragma unroll
    for (int t = 0; t < 8; ++t)
        #pragma unroll
        for (int r = 0; r < 4; ++r)
            myh[(4 * g + r) * 132 + 16 * t + c] = fmaxf(acc[t][r], 0.f);

    // ---- re-fragment h1 as layer-2 A (hi/lo), per-wave, no barrier ----
    uint4 hh[4], hl[4];
    #pragma unroll
    for (int s = 0; s < 4; ++s) {
        F4 f0, f1;
        f0.v = *(const float4*)&myh[c * 132 + 32 * s + 8 * g];
        f1.v = *(const float4*)&myh[c * 132 + 32 * s + 8 * g + 4];
        uint32_t h[8], l[8];
        #pragma unroll
        for (int j = 0; j < 4; ++j) {
            float v0 = f0.f[j];
            h[j] = bf_hi_bits(v0);
            l[j] = bf_hi_bits(v0 - __uint_as_float(h[j] << 16));
            float v1 = f1.f[j];
            h[j + 4] = bf_hi_bits(v1);
            l[j + 4] = bf_hi_bits(v1 - __uint_as_float(h[j + 4] << 16));
        }
        hh[s] = make_uint4(h[0] | (h[1] << 16), h[2] | (h[3] << 16),
                           h[4] | (h[5] << 16), h[6] | (h[7] << 16));
        hl[s] = make_uint4(l[0] | (l[1] << 16), l[2] | (l[3] << 16),
                           l[4] | (l[5] << 16), l[6] | (l[7] << 16));
    }

    // ---- Layer 2: h2 = tanh(h1 @ W2 + b2) ----
    f32x4 acc2[4];
    #pragma unroll
    for (int t = 0; t < 4; ++t) { float bv = b2s[16 * t + c]; acc2[t] = (f32x4){bv, bv, bv, bv}; }
    #pragma unroll
    for (int t = 0; t < 4; ++t) {
        #pragma unroll
        for (int s = 0; s < 4; ++s) {
            U4 bh, bl, ah, al;
            bh.u = w2h[(t * 4 + s) * 64 + lane];
            bl.u = w2l[(t * 4 + s) * 64 + lane];
            ah.u = hh[s]; al.u = hl[s];
            acc2[t] = __builtin_amdgcn_mfma_f32_16x16x32_bf16(ah.s, bh.s, acc2[t], 0, 0, 0);
            acc2[t] = __builtin_amdgcn_mfma_f32_16x16x32_bf16(al.s, bh.s, acc2[t], 0, 0, 0);
            acc2[t] = __builtin_amdgcn_mfma_f32_16x16x32_bf16(ah.s, bl.s, acc2[t], 0, 0, 0);
        }
    }
    // h2 -> same LDS strip (cols 0..63), same wave so ordering is program-order
    #pragma unroll
    for (int t = 0; t < 4; ++t)
        #pragma unroll
        for (int r = 0; r < 4; ++r)
            myh[(4 * g + r) * 132 + 16 * t + c] = tanhf(acc2[t][r]);

    // ---- Layer 3 + F + argmax ----
    const int rowL = lane >> 2, q = lane & 3;
    float a0 = 0.f, a1 = 0.f;
    #pragma unroll
    for (int i = 0; i < 16; ++i) {
        float h = myh[rowL * 132 + 16 * q + i];
        a0 = fmaf(h, W3s[2 * (16 * q + i)], a0);
        a1 = fmaf(h, W3s[2 * (16 * q + i) + 1], a1);
    }
    a0 += __shfl_xor(a0, 1, 64); a0 += __shfl_xor(a0, 2, 64);
    a1 += __shfl_xor(a1, 1, 64); a1 += __shfl_xor(a1, 2, 64);

    double Fv = -INFINITY; int idx = INT_MAX; float o0 = 0.f, o1 = 0.f;
    const int rg = base + 16 * w + rowL;
    if (q == 0 && rg < N) {
        o0 = a0 + b3s[0]; o1 = a1 + b3s[1];
        Fv = Ffunc((double)o0, (double)o1);
        idx = rg;
    }
    #pragma unroll
    for (int m = 32; m > 0; m >>= 1) {
        double Fo = __shfl_xor(Fv, m, 64);
        int io    = __shfl_xor(idx, m, 64);
        float c0  = __shfl_xor(o0, m, 64);
        float c1  = __shfl_xor(o1, m, 64);
        if (Fo > Fv || (Fo == Fv && io < idx)) { Fv = Fo; idx = io; o0 = c0; o1 = c1; }
    }
    if (lane == 0) { candF[w] = Fv; candI[w] = idx; candO[w] = make_float2(o0, o1); }
    __syncthreads();
    if (tid == 0) {
        double bF = candF[0]; int bI = candI[0]; float2 bO = candO[0];
        #pragma unroll
        for (int u = 1; u < 4; ++u) {
            if (candF[u] > bF || (candF[u] == bF && candI[u] < bI)) {
                bF = candF[u]; bI = candI[u]; bO = candO[u];
            }
        }
        wsF[blockIdx.x] = bF; wsI[blockIdx.x] = bI; wsO[blockIdx.x] = bO;
    }
}

__global__ __launch_bounds__(256, 1)
void reduce_cands(const double* __restrict__ wsF, const float2* __restrict__ wsO,
                  const int* __restrict__ wsI, int nB, float* __restrict__ out)
{
    __shared__ double sF[256];
    __shared__ int sI[256];
    __shared__ float2 sO[256];
    const int tid = threadIdx.x;
    double Fv = -INFINITY; int idx = INT_MAX; float2 o = make_float2(0.f, 0.f);
    for (int u = tid; u < nB; u += 256) {
        double f = wsF[u]; int i = wsI[u];
        if (f > Fv || (f == Fv && i < idx)) { Fv = f; idx = i; o = wsO[u]; }
    }
    sF[tid] = Fv; sI[tid] = idx; sO[tid] = o;
    __syncthreads();
    if (tid == 0) {
        for (int u = 1; u < 256; ++u) {
            if (sF[u] > Fv || (sF[u] == Fv && sI[u] < idx)) { Fv = sF[u]; idx = sI[u]; o = sO[u]; }
        }
        out[0] = o.x;
        out[1] = o.y;
    }
}

extern "C" void kernel_launch(void* const* d_in, const int* in_sizes, int n_in,
                              void* d_out, int out_size, void* d_ws, size_t ws_size,
                              hipStream_t stream) {
    const int*   data  = (const int*)d_in[0];
    const float* embed = (const float*)d_in[1];
    const float* W1    = (const float*)d_in[2];
    const float* b1    = (const float*)d_in[3];
    const float* W2    = (const float*)d_in[4];
    const float* b2    = (const float*)d_in[5];
    const float* W3    = (const float*)d_in[6];
    const float* b3    = (const float*)d_in[7];

    const int N = in_sizes[0] / 128;
    const int nTiles = (N + 63) >> 6;

    char* ws = (char*)d_ws;
    uint4* w1h = (uint4*)ws;            // 32 KB (2048 uint4)
    uint4* w1l = w1h + 2048;            // 32 KB
    uint4* w2h = w1l + 2048;            // 16 KB (1024 uint4)
    uint4* w2l = w2h + 1024;            // 16 KB
    char* ws2 = ws + 98304;
    double* wsF = (double*)ws2;
    float2* wsO = (float2*)(ws2 + (size_t)nTiles * 8);
    int*    wsI = (int*)(ws2 + (size_t)nTiles * 16);

    pack_weights<<<12, 256, 0, stream>>>(W1, W2, w1h, w1l, w2h, w2l);
    fused_mlp<<<nTiles, 256, 0, stream>>>(data, embed, b1, b2, W3, b3,
                                          w1h, w1l, w2h, w2l, wsF, wsO, wsI, N);
    reduce_cands<<<1, 256, 0, stream>>>(wsF, wsO, wsI, nTiles, (float*)d_out);
}